// Round 17
// baseline (148.729 us; speedup 1.0000x reference)
//
#include <hip/hip_runtime.h>
#include <hip/hip_fp16.h>

static constexpr float SLOPE = 0.2f;

#define NPB 256          // nodes per bucket
#define NBMAX 512        // max buckets
#define CAP 10240        // packed-edge capacity per bucket (avg ~8184, >20 sigma margin)
#define EPB 8192         // edges per bin block (~21 words/bucket region, line-coalesced)

// ---------------------------------------------------------------------------
// Monotone float<->uint key for exact atomicMax on floats of either sign.
__device__ __forceinline__ unsigned fkey(float f) {
    unsigned u = __float_as_uint(f);
    return (u & 0x80000000u) ? ~u : (u | 0x80000000u);
}
__device__ __forceinline__ float fdekey(unsigned k) {
    unsigned u = (k & 0x80000000u) ? (k & 0x7FFFFFFFu) : ~k;
    return __uint_as_float(u);
}

__device__ __forceinline__ int load_idx(const void* ei, int is64, long long pos) {
    return is64 ? (int)((const long long*)ei)[pos] : ((const int*)ei)[pos];
}

// ---------------------------------------------------------------------------
// Zero the gkeys + bfill workspace (replaces hipMemsetAsync fill node).
__global__ void zero_kernel(unsigned* __restrict__ gkeys, int* __restrict__ bfill) {
    int t = threadIdx.x;
    if (t < 2) gkeys[t] = 0u;
    for (int i = t; i < NBMAX; i += 256) bfill[i] = 0;
}

// ---------------------------------------------------------------------------
// Pass 1: bin edges by dst bucket. LDS-staged sort-by-bucket write-out:
// histogram -> block-local scan -> place into LDS sorted by bucket -> bulk
// reserve -> linear coalesced write-out (writes ~ payload + boundary
// fragments). 1024-thread blocks (16 waves) for latency hiding; EPB=8192
// keeps ~21 contiguous words per bucket region per block. int32 path uses
// contiguous uint4 vector loads (8 edges/thread). Order within a bucket
// region is schedule-dependent; harmless because aggregation is bitwise
// order-independent. int64-vs-int32 edge dtype detected inline (wave-0
// ballot over high words, L2-hot).
__global__ void __launch_bounds__(1024) bin_kernel(
        const void* __restrict__ ei, int* __restrict__ bfill,
        unsigned int* __restrict__ packed, int e, int nb) {
    __shared__ int hist[NBMAX];            // counts, then gbase after reserve
    __shared__ int lbase[NBMAX];           // local exclusive scan
    __shared__ int cur[NBMAX];             // placement cursor
    __shared__ unsigned staged[EPB];       // 32KB bucket-sorted packed words
    __shared__ unsigned short sbkt[EPB];   // 16KB bucket id per slot
    __shared__ int sflag;
    int t = threadIdx.x;
    if (t < 64) {
        unsigned hi = ((const unsigned*)ei)[2 * t + 1];
        unsigned long long b = __ballot(hi != 0u);
        if (t == 0) sflag = (b == 0ull) ? 1 : 0;
    }
    if (t < NBMAX) hist[t] = 0;
    __syncthreads();
    int is64 = sflag;
    long long e0 = (long long)blockIdx.x * EPB;
    int cnt = (int)min((long long)EPB, (long long)e - e0);
    // phase A: load 8 contiguous edges/thread into registers + histogram
    int sr[8], dr[8];
    if (!is64 && t * 8 + 7 < cnt) {
        const uint4* ps = (const uint4*)((const int*)ei + e0) + t * 2;
        const uint4* pd = (const uint4*)((const int*)ei + e + e0) + t * 2;
        uint4 s0 = ps[0], s1 = ps[1], d0 = pd[0], d1 = pd[1];
        sr[0] = s0.x; sr[1] = s0.y; sr[2] = s0.z; sr[3] = s0.w;
        sr[4] = s1.x; sr[5] = s1.y; sr[6] = s1.z; sr[7] = s1.w;
        dr[0] = d0.x; dr[1] = d0.y; dr[2] = d0.z; dr[3] = d0.w;
        dr[4] = d1.x; dr[5] = d1.y; dr[6] = d1.z; dr[7] = d1.w;
    } else {
#pragma unroll
        for (int r = 0; r < 8; ++r) {
            int i = t * 8 + r;
            dr[r] = -1;
            if (i < cnt) {
                sr[r] = load_idx(ei, is64, e0 + i);
                dr[r] = load_idx(ei, is64, (long long)e + e0 + i);
            }
        }
    }
#pragma unroll
    for (int r = 0; r < 8; ++r)
        if (dr[r] >= 0) atomicAdd(&hist[dr[r] >> 8], 1);
    __syncthreads();
    // block-local exclusive scan over NBMAX buckets (thread t owns bucket t)
    int v = (t < NBMAX) ? hist[t] : 0;
    if (t < NBMAX) lbase[t] = v;
    __syncthreads();
    for (int off = 1; off < NBMAX; off <<= 1) {
        int y = (t < NBMAX && t >= off) ? lbase[t - off] : 0;
        __syncthreads();
        if (t < NBMAX) lbase[t] += y;
        __syncthreads();
    }
    if (t < NBMAX) {
        lbase[t] -= v;          // exclusive
        cur[t] = lbase[t];
        hist[t] = (v > 0) ? atomicAdd(&bfill[t], v) : 0;  // hist becomes gbase
    }
    __syncthreads();
    // phase B: place into LDS staged, sorted by bucket
#pragma unroll
    for (int r = 0; r < 8; ++r) {
        if (dr[r] >= 0) {
            int bk = dr[r] >> 8;
            int lp = atomicAdd(&cur[bk], 1);
            staged[lp] = ((unsigned)(dr[r] & 255) << 17) | (unsigned)sr[r];
            sbkt[lp] = (unsigned short)bk;
        }
    }
    __syncthreads();
    // phase C: coalesced linear write-out
    for (int i = t; i < cnt; i += 1024) {
        int bk = sbkt[i];
        int within = hist[bk] + (i - lbase[bk]);
        if (within < CAP)
            packed[(long long)bk * CAP + within] = staged[i];
    }
}

// ---------------------------------------------------------------------------
// Pass 2: one 512-thread block per bucket. Block computes its own csr base
// (reduce over bfill[i<b], L2-hot), LDS per-node histogram + scan -> offs[];
// scatter src ids into the bucket's contiguous csr region. Edge order within
// a node's segment is arbitrary (see aggr_kernel).
__global__ void build_kernel(const unsigned int* __restrict__ packed,
                             const int* __restrict__ bfill,
                             int* __restrict__ offs, int* __restrict__ csr, int n) {
    __shared__ int hist[NPB];
    __shared__ int tmp[NPB];
    __shared__ int cur[NPB];
    __shared__ int red[512];
    int b = blockIdx.x, t = threadIdx.x;
    // base = sum_{i<b} min(bfill[i], CAP)
    int ps = 0;
    for (int i = t; i < b; i += 512) ps += min(bfill[i], CAP);
    red[t] = ps;
    __syncthreads();
    for (int off = 256; off > 0; off >>= 1) {
        if (t < off) red[t] += red[t + off];
        __syncthreads();
    }
    int base = red[0];
    if (t < NPB) hist[t] = 0;
    __syncthreads();
    int cnt = min(bfill[b], CAP);
    long long pb = (long long)b * CAP;
    for (int i = t; i < cnt; i += 512)
        atomicAdd(&hist[packed[pb + i] >> 17], 1);
    __syncthreads();
    int v = (t < NPB) ? hist[t] : 0;
    if (t < NPB) tmp[t] = v;
    __syncthreads();
    for (int off = 1; off < NPB; off <<= 1) {
        int y = (t < NPB && t >= off) ? tmp[t - off] : 0;
        __syncthreads();
        if (t < NPB) tmp[t] += y;
        __syncthreads();
    }
    if (t < NPB) {
        int excl = tmp[t] - v;
        cur[t] = excl;
        int node = b * NPB + t;
        if (node <= n) offs[node] = base + excl;
    }
    __syncthreads();
    for (int i = t; i < cnt; i += 512) {
        unsigned p = packed[pb + i];
        int lp = atomicAdd(&cur[p >> 17], 1);
        csr[base + lp] = (int)(p & 0x1FFFF);
    }
}

// ---------------------------------------------------------------------------
// Per-node feature transform: h = x @ W; alpha_src = h . a_src; alpha_dst = h . a_dst
// Writes h in fp32 (exact: self-term, next layer input) AND fp16 (h16, the
// 3.2MB gather table that fits per-XCD L2). Attention scores as/ad stay fp32.
// Also computes the EXACT global max of alpha_src (order-free) via uint-keyed
// atomicMax — used by aggr_kernel as a softmax upper bound.
template <int NF>
__global__ void feat_kernel(const float* __restrict__ x, const float* __restrict__ W,
                            const float* __restrict__ avs, const float* __restrict__ avd,
                            float* __restrict__ h, __half* __restrict__ h16,
                            float* __restrict__ as, float* __restrict__ ad,
                            unsigned* __restrict__ gkey, int n) {
    __shared__ float sW[NF * 16];
    __shared__ float sa[32];
    __shared__ float red[256];
    int t = threadIdx.x;
    if (t < NF * 16) sW[t] = W[t];
    if (t < 16) sa[t] = avs[t];
    else if (t < 32) sa[t] = avd[t - 16];
    __syncthreads();
    int nid = blockIdx.x * blockDim.x + t;
    float s1 = -1e30f;
    if (nid < n) {
        float xi[NF];
#pragma unroll
        for (int f = 0; f < NF; ++f) xi[f] = x[(long long)nid * NF + f];
        float hv[16];
        s1 = 0.f;
        float s2 = 0.f;
#pragma unroll
        for (int k = 0; k < 16; ++k) {
            float acc = 0.f;
#pragma unroll
            for (int f = 0; f < NF; ++f) acc = fmaf(xi[f], sW[f * 16 + k], acc);
            hv[k] = acc;
            s1 = fmaf(acc, sa[k], s1);
            s2 = fmaf(acc, sa[16 + k], s2);
        }
        float4* hp = (float4*)(h + (long long)nid * 16);
        hp[0] = make_float4(hv[0], hv[1], hv[2], hv[3]);
        hp[1] = make_float4(hv[4], hv[5], hv[6], hv[7]);
        hp[2] = make_float4(hv[8], hv[9], hv[10], hv[11]);
        hp[3] = make_float4(hv[12], hv[13], hv[14], hv[15]);
        // fp16 row (32B, two 16B stores)
        unsigned u[8];
#pragma unroll
        for (int q = 0; q < 8; ++q) {
            __half2 p2 = __halves2half2(__float2half(hv[2 * q]), __float2half(hv[2 * q + 1]));
            u[q] = *(unsigned*)&p2;
        }
        uint4* hp16 = (uint4*)(h16 + (long long)nid * 16);
        hp16[0] = make_uint4(u[0], u[1], u[2], u[3]);
        hp16[1] = make_uint4(u[4], u[5], u[6], u[7]);
        as[nid] = s1;
        ad[nid] = s2;
    }
    red[t] = s1;
    __syncthreads();
    for (int off = 128; off > 0; off >>= 1) {
        if (t < off) red[t] = fmaxf(red[t], red[t + off]);
        __syncthreads();
    }
    if (t == 0) atomicMax(gkey, fkey(red[0]));
}

// ---------------------------------------------------------------------------
// Per-node single-pass softmax aggregation, 16 lanes per node (lane = channel).
// Per 16-edge chunk, lane u computes edge (jb+u)'s weight w ONCE (csr load,
// as gather, leaky, exp). The broadcast phase is BATCHED into three unrolled
// passes: (a) 16 shfls of s into static regs, (b) ALL 16 h16 gathers issued
// back-to-back (16 outstanding VMEM per wave — hides the ~200cy L2 latency
// that serialized the old per-edge load->use chain), (c) shfl w + accumulate.
// Neighbor features gathered from the fp16 table (3.2MB, L2-resident); self
// term uses fp32 h. BITWISE ORDER-INDEPENDENT: normalizer m = leaky(gmax+adn)
// is a global bound (LeakyReLU monotone) => no per-node max pass, exp args
// <= 0. Terms are int32-converted and accumulated in int64 (integer addition
// commutes => identical result for ANY edge permutation). Tail lanes
// contribute exact 0. Per-node exponent boost kb keeps den >= ~2^20 =>
// quantization error ~1e-4.
__global__ void __launch_bounds__(256) aggr_kernel(
        const float* __restrict__ h, const __half* __restrict__ h16,
        const float* __restrict__ as, const float* __restrict__ ad,
        const int* __restrict__ offs, const int* __restrict__ csr,
        const float* __restrict__ bias, const unsigned* __restrict__ gkey,
        float* __restrict__ out, int n, int do_relu) {
    int t = threadIdx.x;
    int node = blockIdx.x * 16 + (t >> 4);
    int k = t & 15;
    if (node >= n) return;
    int gbase = t & 48;                        // group base lane within wave
    const __half* h16k = h16 + k;              // channel-offset base
    float adn = ad[node];
    float gm = fdekey(*gkey) + adn;
    float m = fmaxf(gm, SLOPE * gm);           // leaky(gmax + adn), monotone bound
    float eself = as[node] + adn;
    eself = fmaxf(eself, SLOPE * eself);
    // per-node exponent boost: scale = 2^(21+kb), kb in [0,7]
    float kb = fminf(7.f, fmaxf(0.f, floorf((m - eself) * 1.44269504f)));
    float cc = (21.f + kb) * 0.69314718f - m;  // w = exp(e + cc) = exp(e-m)*2^(21+kb)
    float wself = __expf(eself + cc);
    long long acc = (long long)(int)(wself * h[(long long)node * 16 + k]);
    long long den = 0;
    int j0 = offs[node], j1 = offs[node + 1];
    for (int jb = j0; jb < j1; jb += 16) {
        int jj = jb + k;
        float w = 0.f;
        int s = 0;
        if (jj < j1) {
            s = csr[jj];
            float e2 = as[s] + adn;
            e2 = fmaxf(e2, SLOPE * e2);
            w = __expf(e2 + cc);
        }
        den += (long long)(int)w;
        // (a) gather all 16 src ids into static regs
        int su[16];
#pragma unroll
        for (int u = 0; u < 16; ++u) su[u] = __shfl(s, gbase + u, 64);
        // (b) issue all 16 h16 gathers — 16 outstanding loads per wave
        float hv[16];
#pragma unroll
        for (int u = 0; u < 16; ++u)
            hv[u] = __half2float(h16k[(long long)su[u] * 16]);
        // (c) broadcast w and accumulate
#pragma unroll
        for (int u = 0; u < 16; ++u) {
            float wu = __shfl(w, gbase + u, 64);
            acc += (long long)(int)(wu * hv[u]);
        }
    }
#pragma unroll
    for (int mask = 1; mask < 16; mask <<= 1)
        den += __shfl_xor(den, mask, 64);
    den += (long long)(int)wself;
    float o = (float)acc / (float)den + bias[k];
    if (do_relu) o = fmaxf(o, 0.f);
    out[(long long)node * 16 + k] = o;
}

// ---------------------------------------------------------------------------
extern "C" void kernel_launch(void* const* d_in, const int* in_sizes, int n_in,
                              void* d_out, int out_size, void* d_ws, size_t ws_size,
                              hipStream_t stream) {
    const float* x  = (const float*)d_in[0];
    const void*  ei = d_in[1];
    const float* W1  = (const float*)d_in[2];
    const float* as1 = (const float*)d_in[3];
    const float* ad1 = (const float*)d_in[4];
    const float* b1  = (const float*)d_in[5];
    const float* W2  = (const float*)d_in[6];
    const float* as2 = (const float*)d_in[7];
    const float* ad2 = (const float*)d_in[8];
    const float* b2  = (const float*)d_in[9];
    float* out = (float*)d_out;

    const int n = in_sizes[0] / 14;      // 100000
    const int e = in_sizes[1] / 2;       // 3200000
    const int nb = (n + NPB - 1) / NPB;  // 391 buckets

    char* p = (char*)d_ws;
    auto alloc = [&](size_t bytes) {
        char* r = p;
        p += (bytes + 255) & ~(size_t)255;
        return r;
    };
    unsigned* gkeys  = (unsigned*)alloc(256);          // [0]=gkey1, [1]=gkey2
    int*      bfill  = (int*)alloc(NBMAX * 4);
    unsigned* packed = (unsigned*)alloc((size_t)nb * CAP * 4);
    int*      offs   = (int*)alloc((size_t)(n + 1) * 4);
    int*      csr    = (int*)alloc((size_t)e * 4);
    float*    h      = (float*)alloc((size_t)n * 16 * 4);
    __half*   h16    = (__half*)alloc((size_t)n * 16 * 2);
    float*    h1     = (float*)alloc((size_t)n * 16 * 4);
    float*    asb    = (float*)alloc((size_t)n * 4);
    float*    adb    = (float*)alloc((size_t)n * 4);

    zero_kernel<<<1, 256, 0, stream>>>(gkeys, bfill);
    bin_kernel<<<(e + EPB - 1) / EPB, 1024, 0, stream>>>(ei, bfill, packed, e, nb);
    build_kernel<<<nb, 512, 0, stream>>>(packed, bfill, offs, csr, n);

    // Layer 1
    feat_kernel<14><<<(n + 255) / 256, 256, 0, stream>>>(x, W1, as1, ad1, h, h16, asb, adb, gkeys + 0, n);
    aggr_kernel<<<(n + 15) / 16, 256, 0, stream>>>(h, h16, asb, adb, offs, csr, b1, gkeys + 0, h1, n, 1);
    // Layer 2
    feat_kernel<16><<<(n + 255) / 256, 256, 0, stream>>>(h1, W2, as2, ad2, h, h16, asb, adb, gkeys + 1, n);
    aggr_kernel<<<(n + 15) / 16, 256, 0, stream>>>(h, h16, asb, adb, offs, csr, b2, gkeys + 1, out, n, 0);
}

// Round 18
// 144.834 us; speedup vs baseline: 1.0269x; 1.0269x over previous
//
#include <hip/hip_runtime.h>
#include <hip/hip_fp16.h>

static constexpr float SLOPE = 0.2f;

#define NPB 256          // nodes per bucket
#define NBMAX 512        // max buckets
#define CAP 10240        // packed-edge capacity per bucket (avg ~8184, >20 sigma margin)
#define EPB 8192         // edges per bin block (~21 words/bucket region, line-coalesced)

// ---------------------------------------------------------------------------
// Monotone float<->uint key for exact atomicMax on floats of either sign.
__device__ __forceinline__ unsigned fkey(float f) {
    unsigned u = __float_as_uint(f);
    return (u & 0x80000000u) ? ~u : (u | 0x80000000u);
}
__device__ __forceinline__ float fdekey(unsigned k) {
    unsigned u = (k & 0x80000000u) ? (k & 0x7FFFFFFFu) : ~k;
    return __uint_as_float(u);
}

__device__ __forceinline__ int load_idx(const void* ei, int is64, long long pos) {
    return is64 ? (int)((const long long*)ei)[pos] : ((const int*)ei)[pos];
}

// ---------------------------------------------------------------------------
// Zero the gkeys + bfill workspace (replaces hipMemsetAsync fill node).
__global__ void zero_kernel(unsigned* __restrict__ gkeys, int* __restrict__ bfill) {
    int t = threadIdx.x;
    if (t < 2) gkeys[t] = 0u;
    for (int i = t; i < NBMAX; i += 256) bfill[i] = 0;
}

// ---------------------------------------------------------------------------
// Pass 1: bin edges by dst bucket. LDS-staged sort-by-bucket write-out:
// histogram -> block-local scan -> place into LDS sorted by bucket -> bulk
// reserve -> linear coalesced write-out (writes ~ payload + boundary
// fragments). 1024-thread blocks (16 waves) for latency hiding; EPB=8192
// keeps ~21 contiguous words per bucket region per block. int32 path uses
// contiguous uint4 vector loads (8 edges/thread). Order within a bucket
// region is schedule-dependent; harmless because aggregation is bitwise
// order-independent. int64-vs-int32 edge dtype detected inline (wave-0
// ballot over high words, L2-hot).
__global__ void __launch_bounds__(1024) bin_kernel(
        const void* __restrict__ ei, int* __restrict__ bfill,
        unsigned int* __restrict__ packed, int e, int nb) {
    __shared__ int hist[NBMAX];            // counts, then gbase after reserve
    __shared__ int lbase[NBMAX];           // local exclusive scan
    __shared__ int cur[NBMAX];             // placement cursor
    __shared__ unsigned staged[EPB];       // 32KB bucket-sorted packed words
    __shared__ unsigned short sbkt[EPB];   // 16KB bucket id per slot
    __shared__ int sflag;
    int t = threadIdx.x;
    if (t < 64) {
        unsigned hi = ((const unsigned*)ei)[2 * t + 1];
        unsigned long long b = __ballot(hi != 0u);
        if (t == 0) sflag = (b == 0ull) ? 1 : 0;
    }
    if (t < NBMAX) hist[t] = 0;
    __syncthreads();
    int is64 = sflag;
    long long e0 = (long long)blockIdx.x * EPB;
    int cnt = (int)min((long long)EPB, (long long)e - e0);
    // phase A: load 8 contiguous edges/thread into registers + histogram
    int sr[8], dr[8];
    if (!is64 && t * 8 + 7 < cnt) {
        const uint4* ps = (const uint4*)((const int*)ei + e0) + t * 2;
        const uint4* pd = (const uint4*)((const int*)ei + e + e0) + t * 2;
        uint4 s0 = ps[0], s1 = ps[1], d0 = pd[0], d1 = pd[1];
        sr[0] = s0.x; sr[1] = s0.y; sr[2] = s0.z; sr[3] = s0.w;
        sr[4] = s1.x; sr[5] = s1.y; sr[6] = s1.z; sr[7] = s1.w;
        dr[0] = d0.x; dr[1] = d0.y; dr[2] = d0.z; dr[3] = d0.w;
        dr[4] = d1.x; dr[5] = d1.y; dr[6] = d1.z; dr[7] = d1.w;
    } else {
#pragma unroll
        for (int r = 0; r < 8; ++r) {
            int i = t * 8 + r;
            dr[r] = -1;
            if (i < cnt) {
                sr[r] = load_idx(ei, is64, e0 + i);
                dr[r] = load_idx(ei, is64, (long long)e + e0 + i);
            }
        }
    }
#pragma unroll
    for (int r = 0; r < 8; ++r)
        if (dr[r] >= 0) atomicAdd(&hist[dr[r] >> 8], 1);
    __syncthreads();
    // block-local exclusive scan over NBMAX buckets (thread t owns bucket t)
    int v = (t < NBMAX) ? hist[t] : 0;
    if (t < NBMAX) lbase[t] = v;
    __syncthreads();
    for (int off = 1; off < NBMAX; off <<= 1) {
        int y = (t < NBMAX && t >= off) ? lbase[t - off] : 0;
        __syncthreads();
        if (t < NBMAX) lbase[t] += y;
        __syncthreads();
    }
    if (t < NBMAX) {
        lbase[t] -= v;          // exclusive
        cur[t] = lbase[t];
        hist[t] = (v > 0) ? atomicAdd(&bfill[t], v) : 0;  // hist becomes gbase
    }
    __syncthreads();
    // phase B: place into LDS staged, sorted by bucket
#pragma unroll
    for (int r = 0; r < 8; ++r) {
        if (dr[r] >= 0) {
            int bk = dr[r] >> 8;
            int lp = atomicAdd(&cur[bk], 1);
            staged[lp] = ((unsigned)(dr[r] & 255) << 17) | (unsigned)sr[r];
            sbkt[lp] = (unsigned short)bk;
        }
    }
    __syncthreads();
    // phase C: coalesced linear write-out
    for (int i = t; i < cnt; i += 1024) {
        int bk = sbkt[i];
        int within = hist[bk] + (i - lbase[bk]);
        if (within < CAP)
            packed[(long long)bk * CAP + within] = staged[i];
    }
}

// ---------------------------------------------------------------------------
// Pass 2: one 512-thread block per bucket. Block computes its own csr base
// (reduce over bfill[i<b], L2-hot), LDS per-node histogram + scan -> offs[];
// scatter src ids into the bucket's contiguous csr region. Edge order within
// a node's segment is arbitrary (see aggr_kernel).
__global__ void build_kernel(const unsigned int* __restrict__ packed,
                             const int* __restrict__ bfill,
                             int* __restrict__ offs, int* __restrict__ csr, int n) {
    __shared__ int hist[NPB];
    __shared__ int tmp[NPB];
    __shared__ int cur[NPB];
    __shared__ int red[512];
    int b = blockIdx.x, t = threadIdx.x;
    // base = sum_{i<b} min(bfill[i], CAP)
    int ps = 0;
    for (int i = t; i < b; i += 512) ps += min(bfill[i], CAP);
    red[t] = ps;
    __syncthreads();
    for (int off = 256; off > 0; off >>= 1) {
        if (t < off) red[t] += red[t + off];
        __syncthreads();
    }
    int base = red[0];
    if (t < NPB) hist[t] = 0;
    __syncthreads();
    int cnt = min(bfill[b], CAP);
    long long pb = (long long)b * CAP;
    for (int i = t; i < cnt; i += 512)
        atomicAdd(&hist[packed[pb + i] >> 17], 1);
    __syncthreads();
    int v = (t < NPB) ? hist[t] : 0;
    if (t < NPB) tmp[t] = v;
    __syncthreads();
    for (int off = 1; off < NPB; off <<= 1) {
        int y = (t < NPB && t >= off) ? tmp[t - off] : 0;
        __syncthreads();
        if (t < NPB) tmp[t] += y;
        __syncthreads();
    }
    if (t < NPB) {
        int excl = tmp[t] - v;
        cur[t] = excl;
        int node = b * NPB + t;
        if (node <= n) offs[node] = base + excl;
    }
    __syncthreads();
    for (int i = t; i < cnt; i += 512) {
        unsigned p = packed[pb + i];
        int lp = atomicAdd(&cur[p >> 17], 1);
        csr[base + lp] = (int)(p & 0x1FFFF);
    }
}

// ---------------------------------------------------------------------------
// Per-node feature transform: h = x @ W; alpha_src = h . a_src; alpha_dst = h . a_dst
// Writes h in fp32 (exact: self-term, next layer input) AND fp16 (h16, the
// 3.2MB gather table that fits per-XCD L2). Attention scores as/ad stay fp32.
// Also computes the EXACT global max of alpha_src (order-free) via uint-keyed
// atomicMax — used by aggr_kernel as a softmax upper bound.
template <int NF>
__global__ void feat_kernel(const float* __restrict__ x, const float* __restrict__ W,
                            const float* __restrict__ avs, const float* __restrict__ avd,
                            float* __restrict__ h, __half* __restrict__ h16,
                            float* __restrict__ as, float* __restrict__ ad,
                            unsigned* __restrict__ gkey, int n) {
    __shared__ float sW[NF * 16];
    __shared__ float sa[32];
    __shared__ float red[256];
    int t = threadIdx.x;
    if (t < NF * 16) sW[t] = W[t];
    if (t < 16) sa[t] = avs[t];
    else if (t < 32) sa[t] = avd[t - 16];
    __syncthreads();
    int nid = blockIdx.x * blockDim.x + t;
    float s1 = -1e30f;
    if (nid < n) {
        float xi[NF];
#pragma unroll
        for (int f = 0; f < NF; ++f) xi[f] = x[(long long)nid * NF + f];
        float hv[16];
        s1 = 0.f;
        float s2 = 0.f;
#pragma unroll
        for (int k = 0; k < 16; ++k) {
            float acc = 0.f;
#pragma unroll
            for (int f = 0; f < NF; ++f) acc = fmaf(xi[f], sW[f * 16 + k], acc);
            hv[k] = acc;
            s1 = fmaf(acc, sa[k], s1);
            s2 = fmaf(acc, sa[16 + k], s2);
        }
        float4* hp = (float4*)(h + (long long)nid * 16);
        hp[0] = make_float4(hv[0], hv[1], hv[2], hv[3]);
        hp[1] = make_float4(hv[4], hv[5], hv[6], hv[7]);
        hp[2] = make_float4(hv[8], hv[9], hv[10], hv[11]);
        hp[3] = make_float4(hv[12], hv[13], hv[14], hv[15]);
        // fp16 row (32B, two 16B stores)
        unsigned u[8];
#pragma unroll
        for (int q = 0; q < 8; ++q) {
            __half2 p2 = __halves2half2(__float2half(hv[2 * q]), __float2half(hv[2 * q + 1]));
            u[q] = *(unsigned*)&p2;
        }
        uint4* hp16 = (uint4*)(h16 + (long long)nid * 16);
        hp16[0] = make_uint4(u[0], u[1], u[2], u[3]);
        hp16[1] = make_uint4(u[4], u[5], u[6], u[7]);
        as[nid] = s1;
        ad[nid] = s2;
    }
    red[t] = s1;
    __syncthreads();
    for (int off = 128; off > 0; off >>= 1) {
        if (t < off) red[t] = fmaxf(red[t], red[t + off]);
        __syncthreads();
    }
    if (t == 0) atomicMax(gkey, fkey(red[0]));
}

// ---------------------------------------------------------------------------
// Per-node single-pass softmax aggregation, 16 lanes per node (lane = channel).
// Per 16-edge chunk, lane u computes edge (jb+u)'s weight w ONCE (csr load,
// as gather, leaky, exp). (w,s) pairs are exchanged via a per-group 16-slot
// LDS strip: ONE ds_write_b64 + 16 broadcast ds_read_b64 per chunk (replaces
// 32 ds_bpermute shfls + their address setup; producer and consumers are the
// same wave, so lgkmcnt ordering suffices — no barrier). All 16 h16 gathers
// are issued back-to-back (16 outstanding VMEM per wave) before accumulation.
// Neighbor features gathered from the fp16 table (3.2MB, L2-resident); self
// term uses fp32 h. BITWISE ORDER-INDEPENDENT: normalizer m = leaky(gmax+adn)
// is a global bound (LeakyReLU monotone) => no per-node max pass, exp args
// <= 0. Terms are int32-converted and accumulated in int64 (integer addition
// commutes => identical result for ANY edge permutation). Tail lanes
// contribute exact 0. Per-node exponent boost kb keeps den >= ~2^20 =>
// quantization error ~1e-4.
__global__ void __launch_bounds__(256) aggr_kernel(
        const float* __restrict__ h, const __half* __restrict__ h16,
        const float* __restrict__ as, const float* __restrict__ ad,
        const int* __restrict__ offs, const int* __restrict__ csr,
        const float* __restrict__ bias, const unsigned* __restrict__ gkey,
        float* __restrict__ out, int n, int do_relu) {
    __shared__ unsigned long long pairs[256];  // 16 groups x 16 slots, 2KB
    int t = threadIdx.x;
    int node = blockIdx.x * 16 + (t >> 4);
    int k = t & 15;
    if (node >= n) return;
    int g16 = t & 240;                         // group base slot in pairs[]
    const __half* h16k = h16 + k;              // channel-offset base
    float adn = ad[node];
    float gm = fdekey(*gkey) + adn;
    float m = fmaxf(gm, SLOPE * gm);           // leaky(gmax + adn), monotone bound
    float eself = as[node] + adn;
    eself = fmaxf(eself, SLOPE * eself);
    // per-node exponent boost: scale = 2^(21+kb), kb in [0,7]
    float kb = fminf(7.f, fmaxf(0.f, floorf((m - eself) * 1.44269504f)));
    float cc = (21.f + kb) * 0.69314718f - m;  // w = exp(e + cc) = exp(e-m)*2^(21+kb)
    float wself = __expf(eself + cc);
    long long acc = (long long)(int)(wself * h[(long long)node * 16 + k]);
    long long den = 0;
    int j0 = offs[node], j1 = offs[node + 1];
    for (int jb = j0; jb < j1; jb += 16) {
        int jj = jb + k;
        float w = 0.f;
        int s = 0;
        if (jj < j1) {
            s = csr[jj];
            float e2 = as[s] + adn;
            e2 = fmaxf(e2, SLOPE * e2);
            w = __expf(e2 + cc);
        }
        den += (long long)(int)w;
        // publish (w,s) to the group's LDS strip (same-wave, no barrier)
        pairs[g16 | k] = ((unsigned long long)__float_as_uint(w) << 32) | (unsigned)s;
        // read all 16 pairs (broadcast within group, compile-time offsets)
        int su[16];
        float wu[16];
#pragma unroll
        for (int u = 0; u < 16; ++u) {
            unsigned long long p = pairs[g16 | u];
            su[u] = (int)(unsigned)p;
            wu[u] = __uint_as_float((unsigned)(p >> 32));
        }
        // issue all 16 h16 gathers — 16 outstanding loads per wave
        float hv[16];
#pragma unroll
        for (int u = 0; u < 16; ++u)
            hv[u] = __half2float(h16k[(long long)su[u] * 16]);
        // accumulate
#pragma unroll
        for (int u = 0; u < 16; ++u)
            acc += (long long)(int)(wu[u] * hv[u]);
    }
#pragma unroll
    for (int mask = 1; mask < 16; mask <<= 1)
        den += __shfl_xor(den, mask, 64);
    den += (long long)(int)wself;
    float o = (float)acc / (float)den + bias[k];
    if (do_relu) o = fmaxf(o, 0.f);
    out[(long long)node * 16 + k] = o;
}

// ---------------------------------------------------------------------------
extern "C" void kernel_launch(void* const* d_in, const int* in_sizes, int n_in,
                              void* d_out, int out_size, void* d_ws, size_t ws_size,
                              hipStream_t stream) {
    const float* x  = (const float*)d_in[0];
    const void*  ei = d_in[1];
    const float* W1  = (const float*)d_in[2];
    const float* as1 = (const float*)d_in[3];
    const float* ad1 = (const float*)d_in[4];
    const float* b1  = (const float*)d_in[5];
    const float* W2  = (const float*)d_in[6];
    const float* as2 = (const float*)d_in[7];
    const float* ad2 = (const float*)d_in[8];
    const float* b2  = (const float*)d_in[9];
    float* out = (float*)d_out;

    const int n = in_sizes[0] / 14;      // 100000
    const int e = in_sizes[1] / 2;       // 3200000
    const int nb = (n + NPB - 1) / NPB;  // 391 buckets

    char* p = (char*)d_ws;
    auto alloc = [&](size_t bytes) {
        char* r = p;
        p += (bytes + 255) & ~(size_t)255;
        return r;
    };
    unsigned* gkeys  = (unsigned*)alloc(256);          // [0]=gkey1, [1]=gkey2
    int*      bfill  = (int*)alloc(NBMAX * 4);
    unsigned* packed = (unsigned*)alloc((size_t)nb * CAP * 4);
    int*      offs   = (int*)alloc((size_t)(n + 1) * 4);
    int*      csr    = (int*)alloc((size_t)e * 4);
    float*    h      = (float*)alloc((size_t)n * 16 * 4);
    __half*   h16    = (__half*)alloc((size_t)n * 16 * 2);
    float*    h1     = (float*)alloc((size_t)n * 16 * 4);
    float*    asb    = (float*)alloc((size_t)n * 4);
    float*    adb    = (float*)alloc((size_t)n * 4);

    zero_kernel<<<1, 256, 0, stream>>>(gkeys, bfill);
    bin_kernel<<<(e + EPB - 1) / EPB, 1024, 0, stream>>>(ei, bfill, packed, e, nb);
    build_kernel<<<nb, 512, 0, stream>>>(packed, bfill, offs, csr, n);

    // Layer 1
    feat_kernel<14><<<(n + 255) / 256, 256, 0, stream>>>(x, W1, as1, ad1, h, h16, asb, adb, gkeys + 0, n);
    aggr_kernel<<<(n + 15) / 16, 256, 0, stream>>>(h, h16, asb, adb, offs, csr, b1, gkeys + 0, h1, n, 1);
    // Layer 2
    feat_kernel<16><<<(n + 255) / 256, 256, 0, stream>>>(h1, W2, as2, ad2, h, h16, asb, adb, gkeys + 1, n);
    aggr_kernel<<<(n + 15) / 16, 256, 0, stream>>>(h, h16, asb, adb, offs, csr, b2, gkeys + 1, out, n, 0);
}

// Round 19
// 135.514 us; speedup vs baseline: 1.0975x; 1.0688x over previous
//
#include <hip/hip_runtime.h>
#include <hip/hip_fp16.h>

static constexpr float SLOPE = 0.2f;

#define NPB 256          // nodes per bucket
#define NBMAX 512        // max buckets
#define CAP 10240        // packed-edge capacity per bucket (avg ~8184, >20 sigma margin)
#define EPB 8192         // edges per bin block (~21 words/bucket region, line-coalesced)

// ---------------------------------------------------------------------------
// Monotone float<->uint key for exact atomicMax on floats of either sign.
__device__ __forceinline__ unsigned fkey(float f) {
    unsigned u = __float_as_uint(f);
    return (u & 0x80000000u) ? ~u : (u | 0x80000000u);
}
__device__ __forceinline__ float fdekey(unsigned k) {
    unsigned u = (k & 0x80000000u) ? (k & 0x7FFFFFFFu) : ~k;
    return __uint_as_float(u);
}

__device__ __forceinline__ int load_idx(const void* ei, int is64, long long pos) {
    return is64 ? (int)((const long long*)ei)[pos] : ((const int*)ei)[pos];
}

// ---------------------------------------------------------------------------
// Zero the gkeys + bfill workspace (replaces hipMemsetAsync fill node).
__global__ void zero_kernel(unsigned* __restrict__ gkeys, int* __restrict__ bfill) {
    int t = threadIdx.x;
    if (t < 2) gkeys[t] = 0u;
    for (int i = t; i < NBMAX; i += 256) bfill[i] = 0;
}

// ---------------------------------------------------------------------------
// Pass 1: bin edges by dst bucket. LDS-staged sort-by-bucket write-out:
// histogram -> block-local scan -> place into LDS sorted by bucket -> bulk
// reserve -> linear coalesced write-out (writes ~ payload + boundary
// fragments). 1024-thread blocks (16 waves) for latency hiding; EPB=8192
// keeps ~21 contiguous words per bucket region per block. int32 path uses
// contiguous uint4 vector loads (8 edges/thread). Order within a bucket
// region is schedule-dependent; harmless because aggregation is bitwise
// order-independent. int64-vs-int32 edge dtype detected inline (wave-0
// ballot over high words, L2-hot).
__global__ void __launch_bounds__(1024) bin_kernel(
        const void* __restrict__ ei, int* __restrict__ bfill,
        unsigned int* __restrict__ packed, int e, int nb) {
    __shared__ int hist[NBMAX];            // counts, then gbase after reserve
    __shared__ int lbase[NBMAX];           // local exclusive scan
    __shared__ int cur[NBMAX];             // placement cursor
    __shared__ unsigned staged[EPB];       // 32KB bucket-sorted packed words
    __shared__ unsigned short sbkt[EPB];   // 16KB bucket id per slot
    __shared__ int sflag;
    int t = threadIdx.x;
    if (t < 64) {
        unsigned hi = ((const unsigned*)ei)[2 * t + 1];
        unsigned long long b = __ballot(hi != 0u);
        if (t == 0) sflag = (b == 0ull) ? 1 : 0;
    }
    if (t < NBMAX) hist[t] = 0;
    __syncthreads();
    int is64 = sflag;
    long long e0 = (long long)blockIdx.x * EPB;
    int cnt = (int)min((long long)EPB, (long long)e - e0);
    // phase A: load 8 contiguous edges/thread into registers + histogram
    int sr[8], dr[8];
    if (!is64 && t * 8 + 7 < cnt) {
        const uint4* ps = (const uint4*)((const int*)ei + e0) + t * 2;
        const uint4* pd = (const uint4*)((const int*)ei + e + e0) + t * 2;
        uint4 s0 = ps[0], s1 = ps[1], d0 = pd[0], d1 = pd[1];
        sr[0] = s0.x; sr[1] = s0.y; sr[2] = s0.z; sr[3] = s0.w;
        sr[4] = s1.x; sr[5] = s1.y; sr[6] = s1.z; sr[7] = s1.w;
        dr[0] = d0.x; dr[1] = d0.y; dr[2] = d0.z; dr[3] = d0.w;
        dr[4] = d1.x; dr[5] = d1.y; dr[6] = d1.z; dr[7] = d1.w;
    } else {
#pragma unroll
        for (int r = 0; r < 8; ++r) {
            int i = t * 8 + r;
            dr[r] = -1;
            if (i < cnt) {
                sr[r] = load_idx(ei, is64, e0 + i);
                dr[r] = load_idx(ei, is64, (long long)e + e0 + i);
            }
        }
    }
#pragma unroll
    for (int r = 0; r < 8; ++r)
        if (dr[r] >= 0) atomicAdd(&hist[dr[r] >> 8], 1);
    __syncthreads();
    // block-local exclusive scan over NBMAX buckets (thread t owns bucket t)
    int v = (t < NBMAX) ? hist[t] : 0;
    if (t < NBMAX) lbase[t] = v;
    __syncthreads();
    for (int off = 1; off < NBMAX; off <<= 1) {
        int y = (t < NBMAX && t >= off) ? lbase[t - off] : 0;
        __syncthreads();
        if (t < NBMAX) lbase[t] += y;
        __syncthreads();
    }
    if (t < NBMAX) {
        lbase[t] -= v;          // exclusive
        cur[t] = lbase[t];
        hist[t] = (v > 0) ? atomicAdd(&bfill[t], v) : 0;  // hist becomes gbase
    }
    __syncthreads();
    // phase B: place into LDS staged, sorted by bucket
#pragma unroll
    for (int r = 0; r < 8; ++r) {
        if (dr[r] >= 0) {
            int bk = dr[r] >> 8;
            int lp = atomicAdd(&cur[bk], 1);
            staged[lp] = ((unsigned)(dr[r] & 255) << 17) | (unsigned)sr[r];
            sbkt[lp] = (unsigned short)bk;
        }
    }
    __syncthreads();
    // phase C: coalesced linear write-out
    for (int i = t; i < cnt; i += 1024) {
        int bk = sbkt[i];
        int within = hist[bk] + (i - lbase[bk]);
        if (within < CAP)
            packed[(long long)bk * CAP + within] = staged[i];
    }
}

// ---------------------------------------------------------------------------
// Per-node feature transform: h = x @ W; alpha_src = h . a_src; alpha_dst = h . a_dst
// Writes h in fp32 (exact: self-term, next layer input) AND fp16 (h16, the
// 3.2MB gather table that fits per-XCD L2). Attention scores as/ad stay fp32.
// Also computes the EXACT global max of alpha_src (order-free) via uint-keyed
// atomicMax — used by aggr_kernel as a softmax upper bound.
template <int NF>
__global__ void feat_kernel(const float* __restrict__ x, const float* __restrict__ W,
                            const float* __restrict__ avs, const float* __restrict__ avd,
                            float* __restrict__ h, __half* __restrict__ h16,
                            float* __restrict__ as, float* __restrict__ ad,
                            unsigned* __restrict__ gkey, int n) {
    __shared__ float sW[NF * 16];
    __shared__ float sa[32];
    __shared__ float red[256];
    int t = threadIdx.x;
    if (t < NF * 16) sW[t] = W[t];
    if (t < 16) sa[t] = avs[t];
    else if (t < 32) sa[t] = avd[t - 16];
    __syncthreads();
    int nid = blockIdx.x * blockDim.x + t;
    float s1 = -1e30f;
    if (nid < n) {
        float xi[NF];
#pragma unroll
        for (int f = 0; f < NF; ++f) xi[f] = x[(long long)nid * NF + f];
        float hv[16];
        s1 = 0.f;
        float s2 = 0.f;
#pragma unroll
        for (int k = 0; k < 16; ++k) {
            float acc = 0.f;
#pragma unroll
            for (int f = 0; f < NF; ++f) acc = fmaf(xi[f], sW[f * 16 + k], acc);
            hv[k] = acc;
            s1 = fmaf(acc, sa[k], s1);
            s2 = fmaf(acc, sa[16 + k], s2);
        }
        float4* hp = (float4*)(h + (long long)nid * 16);
        hp[0] = make_float4(hv[0], hv[1], hv[2], hv[3]);
        hp[1] = make_float4(hv[4], hv[5], hv[6], hv[7]);
        hp[2] = make_float4(hv[8], hv[9], hv[10], hv[11]);
        hp[3] = make_float4(hv[12], hv[13], hv[14], hv[15]);
        // fp16 row (32B, two 16B stores)
        unsigned u[8];
#pragma unroll
        for (int q = 0; q < 8; ++q) {
            __half2 p2 = __halves2half2(__float2half(hv[2 * q]), __float2half(hv[2 * q + 1]));
            u[q] = *(unsigned*)&p2;
        }
        uint4* hp16 = (uint4*)(h16 + (long long)nid * 16);
        hp16[0] = make_uint4(u[0], u[1], u[2], u[3]);
        hp16[1] = make_uint4(u[4], u[5], u[6], u[7]);
        as[nid] = s1;
        ad[nid] = s2;
    }
    red[t] = s1;
    __syncthreads();
    for (int off = 128; off > 0; off >>= 1) {
        if (t < off) red[t] = fmaxf(red[t], red[t + off]);
        __syncthreads();
    }
    if (t == 0) atomicMax(gkey, fkey(red[0]));
}

// ---------------------------------------------------------------------------
// EDGE-PARALLEL softmax aggregation, one block per bucket, straight from the
// packed (dst_local<<17|src) array — csr/offs/build pass no longer needed.
// Each thread owns whole edges (64 independent edges per wave): 1 packed
// load + 1 as gather + ONE vectorized 32B h16-row load (2x uint4), then 17
// fire-and-forget LDS int64 atomics (ds_add_u64 has no return => no wave
// stall). acc stride is 17 qwords/node to break the 128B bank wrap =>
// (dl+k)%16 bank-pair spread (~4-way). Self term folded into the init phase
// from exact fp32 h. BITWISE ORDER-INDEPENDENT: integer atomic adds commute
// exactly => identical result for ANY edge order/schedule; normalizer
// m = leaky(gmax+adn) is a global bound (LeakyReLU monotone) so exp args
// <= 0; per-node exponent boost kb keeps den >= ~2^20 (quantization ~1e-4,
// terms < 2^31).
__global__ void __launch_bounds__(512) aggr_kernel(
        const float* __restrict__ h, const __half* __restrict__ h16,
        const float* __restrict__ as, const float* __restrict__ ad,
        const unsigned* __restrict__ packed, const int* __restrict__ bfill,
        const float* __restrict__ bias, const unsigned* __restrict__ gkey,
        float* __restrict__ out, int n, int do_relu) {
    __shared__ unsigned long long accS[NPB * 17];  // 34816 B, stride 17 anti-conflict
    __shared__ unsigned long long denS[NPB];       // 2 KB
    __shared__ float ccS[NPB];                     // 1 KB
    __shared__ float adnS[NPB];                    // 1 KB
    int b = blockIdx.x, t = threadIdx.x;
    float gmax = fdekey(*gkey);
    // init: per-node state + self term (threads 0..255, one node each)
    if (t < NPB) {
        int node = b * NPB + t;
        if (node < n) {
            float adn = ad[node];
            adnS[t] = adn;
            float gm = gmax + adn;
            float m = fmaxf(gm, SLOPE * gm);       // leaky(gmax + adn)
            float es = as[node] + adn;
            es = fmaxf(es, SLOPE * es);
            float kb = fminf(7.f, fmaxf(0.f, floorf((m - es) * 1.44269504f)));
            float cc = (21.f + kb) * 0.69314718f - m;
            ccS[t] = cc;
            float ws = __expf(es + cc);
            denS[t] = (unsigned long long)(long long)(int)ws;
            const float4* hp = (const float4*)(h + (long long)node * 16);
            float4 h0 = hp[0], h1v = hp[1], h2v = hp[2], h3v = hp[3];
            float hv[16] = {h0.x, h0.y, h0.z, h0.w, h1v.x, h1v.y, h1v.z, h1v.w,
                            h2v.x, h2v.y, h2v.z, h2v.w, h3v.x, h3v.y, h3v.z, h3v.w};
#pragma unroll
            for (int k = 0; k < 16; ++k)
                accS[t * 17 + k] = (unsigned long long)(long long)(int)(ws * hv[k]);
        }
    }
    __syncthreads();
    // edge-parallel accumulation
    int cnt = min(bfill[b], CAP);
    long long pb = (long long)b * CAP;
    for (int j = t; j < cnt; j += 512) {
        unsigned p = packed[pb + j];
        int dl = p >> 17;
        int s = (int)(p & 0x1FFFF);
        float e2 = as[s] + adnS[dl];
        e2 = fmaxf(e2, SLOPE * e2);
        float w = __expf(e2 + ccS[dl]);
        atomicAdd(&denS[dl], (unsigned long long)(long long)(int)w);
        const uint4* hr = (const uint4*)(h16 + (long long)s * 16);
        uint4 r0 = hr[0], r1 = hr[1];
        unsigned rr[8] = {r0.x, r0.y, r0.z, r0.w, r1.x, r1.y, r1.z, r1.w};
        int base = dl * 17;
#pragma unroll
        for (int q = 0; q < 8; ++q) {
            __half2 h2 = *(__half2*)&rr[q];
            float2 f = __half22float2(h2);
            atomicAdd(&accS[base + 2 * q],
                      (unsigned long long)(long long)(int)(w * f.x));
            atomicAdd(&accS[base + 2 * q + 1],
                      (unsigned long long)(long long)(int)(w * f.y));
        }
    }
    __syncthreads();
    // output: divide + bias (+ relu), coalesced
    for (int idx = t; idx < NPB * 16; idx += 512) {
        int i = idx >> 4, k = idx & 15;
        int node = b * NPB + i;
        if (node < n) {
            float o = (float)(long long)accS[i * 17 + k] /
                      (float)(long long)denS[i] + bias[k];
            if (do_relu) o = fmaxf(o, 0.f);
            out[(long long)node * 16 + k] = o;
        }
    }
}

// ---------------------------------------------------------------------------
extern "C" void kernel_launch(void* const* d_in, const int* in_sizes, int n_in,
                              void* d_out, int out_size, void* d_ws, size_t ws_size,
                              hipStream_t stream) {
    const float* x  = (const float*)d_in[0];
    const void*  ei = d_in[1];
    const float* W1  = (const float*)d_in[2];
    const float* as1 = (const float*)d_in[3];
    const float* ad1 = (const float*)d_in[4];
    const float* b1  = (const float*)d_in[5];
    const float* W2  = (const float*)d_in[6];
    const float* as2 = (const float*)d_in[7];
    const float* ad2 = (const float*)d_in[8];
    const float* b2  = (const float*)d_in[9];
    float* out = (float*)d_out;

    const int n = in_sizes[0] / 14;      // 100000
    const int e = in_sizes[1] / 2;       // 3200000
    const int nb = (n + NPB - 1) / NPB;  // 391 buckets

    char* p = (char*)d_ws;
    auto alloc = [&](size_t bytes) {
        char* r = p;
        p += (bytes + 255) & ~(size_t)255;
        return r;
    };
    unsigned* gkeys  = (unsigned*)alloc(256);          // [0]=gkey1, [1]=gkey2
    int*      bfill  = (int*)alloc(NBMAX * 4);
    unsigned* packed = (unsigned*)alloc((size_t)nb * CAP * 4);
    float*    h      = (float*)alloc((size_t)n * 16 * 4);
    __half*   h16    = (__half*)alloc((size_t)n * 16 * 2);
    float*    h1     = (float*)alloc((size_t)n * 16 * 4);
    float*    asb    = (float*)alloc((size_t)n * 4);
    float*    adb    = (float*)alloc((size_t)n * 4);

    zero_kernel<<<1, 256, 0, stream>>>(gkeys, bfill);
    bin_kernel<<<(e + EPB - 1) / EPB, 1024, 0, stream>>>(ei, bfill, packed, e, nb);

    // Layer 1
    feat_kernel<14><<<(n + 255) / 256, 256, 0, stream>>>(x, W1, as1, ad1, h, h16, asb, adb, gkeys + 0, n);
    aggr_kernel<<<nb, 512, 0, stream>>>(h, h16, asb, adb, packed, bfill, b1, gkeys + 0, h1, n, 1);
    // Layer 2
    feat_kernel<16><<<(n + 255) / 256, 256, 0, stream>>>(h1, W2, as2, ad2, h, h16, asb, adb, gkeys + 1, n);
    aggr_kernel<<<nb, 512, 0, stream>>>(h, h16, asb, adb, packed, bfill, b2, gkeys + 1, out, n, 0);
}